// Round 15
// baseline (79.590 us; speedup 1.0000x reference)
//
#include <hip/hip_runtime.h>
#include <hip/hip_bf16.h>
#include <math.h>

// out[b,f,t] = sum_l sig[b,l] * win[t,l] * cos(2*pi*fv[f]*l/8192)
// R15 = R14 + 4-b amortization + K-split-2 + atomic epilogue:
//  - block = 32t x 32f x 4b tile over HALF of K (kh in {0,1}); grid 256
//    (bq8 x th4 x fh4 x kh2) x 512 thr; wave K = 512 -> 16 sub-steps
//    (half R14's serial depth), fragment-gen VALU/MFMA 7 -> 4.5.
//  - out zeroed via hipMemsetAsync, kh-halves combined with atomicAdd f32
//    (2 contributions/element -> commutative, deterministic).
//  - Sg[4][4096] f16 (32 KB) unioned with the post-loop reduce buffer.
// Gaussian: multiplicative recurrence; cos: stride-32 Chebyshev ping-pong
// seeded from exact integer phase mod 8192 (R0-verified fv/tc).

#define L_ 8192
#define B_ 32

typedef _Float16 half8 __attribute__((ext_vector_type(8)));
typedef __fp16 fp16x2 __attribute__((ext_vector_type(2)));
typedef float float2v __attribute__((ext_vector_type(2)));
typedef float float4v __attribute__((ext_vector_type(4)));

#define H_ 0.001220703125f                 // 1/819.2 = 5/4096 (exact)
#define CSTEP_ 7.66990393942594528198e-4f  // 2*pi/8192

__global__ __launch_bounds__(512, 2) void gabor_kernel(
    const float* __restrict__ signal, float* __restrict__ out) {
  const int bx = blockIdx.x;  // 256 = kh2 * fh4 * th4 * bq8
  const int kh = bx & 1;
  const int fh = (bx >> 1) & 3;
  const int th = (bx >> 3) & 3;
  const int bq = (bx >> 5) & 7;  // 4 b's: 4*bq .. 4*bq+3
  const int tid = threadIdx.x;   // 512
  const int lane = tid & 63;
  const int wv = tid >> 6;       // 0..7
  const int frow = lane & 15;
  const int quad = lane >> 4;

  // LDS union: Sg lives during the K-loop, Acc (reduction) after it.
  __shared__ __align__(16) char smraw[32768];
  _Float16(*Sg)[4096] = (_Float16(*)[4096])smraw;   // [4][4096] f16, 32 KB
  float4v(*Acc)[64][4] = (float4v(*)[64][4])smraw;  // [8][64][4], 32 KB

  // ---- stage sig rows 4bq..4bq+3, K-half kh (once) ----
#pragma unroll
  for (int bi = 0; bi < 4; ++bi) {
    const float* srow =
        signal + (size_t)(4 * bq + bi) * L_ + kh * 4096 + tid * 8;
    float4v s0 = *(const float4v*)srow;
    float4v s1 = *(const float4v*)(srow + 4);
    union { fp16x2 h2[4]; half8 h8; } sh;
    sh.h2[0] = __builtin_amdgcn_cvt_pkrtz(s0[0], s0[1]);
    sh.h2[1] = __builtin_amdgcn_cvt_pkrtz(s0[2], s0[3]);
    sh.h2[2] = __builtin_amdgcn_cvt_pkrtz(s1[0], s1[1]);
    sh.h2[3] = __builtin_amdgcn_cvt_pkrtz(s1[2], s1[3]);
    *(half8*)&Sg[bi][tid * 8] = sh.h8;
  }
  __syncthreads();

  const int t0 = th * 32;
  const int f0 = fh * 32;
  const int kloc0 = wv * 512 + quad * 8;  // k within this block's half
  const int k0g = kh * 4096 + kloc0;      // global k of element j=0, step 0

  // ---- per-lane fragment state (packed f32 pairs) ----
  float2v w2[2][4], Rw2[2][4];   // Gaussian value + step-ratio
  float2v cE2[2][4], cO2[2][4];  // Chebyshev ping-pong (even/odd step)
  float2v K32v[2];
  const float2v Q32v = {0.99847528338432312012f,
                        0.99847528338432312012f};  // exp(-1024*H^2)
#pragma unroll
  for (int fr = 0; fr < 2; ++fr) {
    const float tc = truncf((float)(t0 + fr * 16 + frow) * (8191.0f / 127.0f));
    const int fv = (int)((float)(f0 + fr * 16 + frow) * (4096.0f / 127.0f));
    const float K32 = 2.0f * __cosf((float)((fv * 32) & (L_ - 1)) * CSTEP_);
    K32v[fr] = (float2v){K32, K32};
#pragma unroll
    for (int q = 0; q < 4; ++q) {
#pragma unroll
      for (int h = 0; h < 2; ++h) {
        const int j = 2 * q + h;
        const float x = ((float)(k0g + j) - tc) * H_;
        w2[fr][q][h] = __expf(-0.5f * x * x);
        // ratio for k += 32: exp(-32*H*x - 512*H^2)
        Rw2[fr][q][h] =
            __expf(__builtin_fmaf(-0.0390625f, x, -7.62939453125e-4f));
        cE2[fr][q][h] = __cosf((float)((fv * (k0g + j)) & (L_ - 1)) * CSTEP_);
        // value at k-32 (k0g+j+8160 == k0g+j-32 mod 8192)
        cO2[fr][q][h] =
            __cosf((float)((fv * (k0g + j + 8160)) & (L_ - 1)) * CSTEP_);
      }
    }
  }

  float4v acc[4][2][2];  // [bi][fr1 t][fr2 f]
#pragma unroll
  for (int bi = 0; bi < 4; ++bi)
#pragma unroll
    for (int i = 0; i < 2; ++i)
#pragma unroll
      for (int j = 0; j < 2; ++j) acc[bi][i][j] = (float4v)(0.0f);

  union H8 { fp16x2 h2[4]; half8 h8; };

  // ---- 16 K-steps: 8 rolled iterations x 2 ping-pong sub-steps ----
#pragma unroll 1
  for (int p = 0; p < 8; ++p) {
    // prefetch sig fragments for both sub-steps (4 b x 2)
    half8 sgE[4], sgO[4];
    const int kkE = kloc0 + (2 * p) * 32;
#pragma unroll
    for (int bi = 0; bi < 4; ++bi) {
      sgE[bi] = *(const half8*)&Sg[bi][kkE];
      sgO[bi] = *(const half8*)&Sg[bi][kkE + 32];
    }
    // -- even sub-step: fragments from w2, cE2 --
    {
      H8 ha[2], hc[2];
#pragma unroll
      for (int fr = 0; fr < 2; ++fr)
#pragma unroll
        for (int q = 0; q < 4; ++q) {
          ha[fr].h2[q] = __builtin_amdgcn_cvt_pkrtz(w2[fr][q][0], w2[fr][q][1]);
          hc[fr].h2[q] = __builtin_amdgcn_cvt_pkrtz(cE2[fr][q][0], cE2[fr][q][1]);
        }
      // advance recurrences early (next sub-step's serial chain overlaps MFMA)
#pragma unroll
      for (int fr = 0; fr < 2; ++fr)
#pragma unroll
        for (int q = 0; q < 4; ++q) {
          w2[fr][q] *= Rw2[fr][q];
          Rw2[fr][q] *= Q32v;
          cO2[fr][q] = __builtin_elementwise_fma(K32v[fr], cE2[fr][q], -cO2[fr][q]);
        }
#pragma unroll
      for (int bi = 0; bi < 4; ++bi) {
#pragma unroll
        for (int fr2 = 0; fr2 < 2; ++fr2) {
          const half8 hbf = hc[fr2].h8 * sgE[bi];
          acc[bi][0][fr2] = __builtin_amdgcn_mfma_f32_16x16x32_f16(
              ha[0].h8, hbf, acc[bi][0][fr2], 0, 0, 0);
          acc[bi][1][fr2] = __builtin_amdgcn_mfma_f32_16x16x32_f16(
              ha[1].h8, hbf, acc[bi][1][fr2], 0, 0, 0);
        }
      }
    }
    // -- odd sub-step: fragments from w2 (advanced), cO2 --
    {
      H8 ha[2], hc[2];
#pragma unroll
      for (int fr = 0; fr < 2; ++fr)
#pragma unroll
        for (int q = 0; q < 4; ++q) {
          ha[fr].h2[q] = __builtin_amdgcn_cvt_pkrtz(w2[fr][q][0], w2[fr][q][1]);
          hc[fr].h2[q] = __builtin_amdgcn_cvt_pkrtz(cO2[fr][q][0], cO2[fr][q][1]);
        }
#pragma unroll
      for (int fr = 0; fr < 2; ++fr)
#pragma unroll
        for (int q = 0; q < 4; ++q) {
          w2[fr][q] *= Rw2[fr][q];
          Rw2[fr][q] *= Q32v;
          cE2[fr][q] = __builtin_elementwise_fma(K32v[fr], cO2[fr][q], -cE2[fr][q]);
        }
#pragma unroll
      for (int bi = 0; bi < 4; ++bi) {
#pragma unroll
        for (int fr2 = 0; fr2 < 2; ++fr2) {
          const half8 hbf = hc[fr2].h8 * sgO[bi];
          acc[bi][0][fr2] = __builtin_amdgcn_mfma_f32_16x16x32_f16(
              ha[0].h8, hbf, acc[bi][0][fr2], 0, 0, 0);
          acc[bi][1][fr2] = __builtin_amdgcn_mfma_f32_16x16x32_f16(
              ha[1].h8, hbf, acc[bi][1][fr2], 0, 0, 0);
        }
      }
    }
  }

  // ---- 4-phase reduction through LDS (reusing Sg space) + atomic add ----
  // D frag: col(f)=lane&15, row(t)=quad*4+reg (reg contiguous in t)
#pragma unroll
  for (int bi = 0; bi < 4; ++bi) {
    __syncthreads();  // previous LDS use complete
#pragma unroll
    for (int i4 = 0; i4 < 4; ++i4)
      Acc[wv][lane][i4] = acc[bi][i4 >> 1][i4 & 1];  // i4 = fr1*2 + fr2
    __syncthreads();
    if (wv < 4) {
      float4v sum = Acc[0][lane][wv];
#pragma unroll
      for (int w = 1; w < 8; ++w) sum += Acc[w][lane][wv];
      const int fr1 = wv >> 1, fr2 = wv & 1;
      const int f = f0 + fr2 * 16 + frow;
      const int t = t0 + fr1 * 16 + quad * 4;
      float* o = out + ((size_t)((4 * bq + bi) * 128 + f)) * 128 + t;
#pragma unroll
      for (int r = 0; r < 4; ++r) atomicAdd(o + r, sum[r]);
    }
  }
}

extern "C" void kernel_launch(void* const* d_in, const int* in_sizes, int n_in,
                              void* d_out, int out_size, void* d_ws, size_t ws_size,
                              hipStream_t stream) {
  const float* signal = (const float*)d_in[0];
  float* out = (float*)d_out;
  hipMemsetAsync(out, 0, (size_t)out_size * sizeof(float), stream);
  gabor_kernel<<<dim3(256), dim3(512), 0, stream>>>(signal, out);
}

// Round 16
// 67.798 us; speedup vs baseline: 1.1739x; 1.1739x over previous
//
#include <hip/hip_runtime.h>
#include <hip/hip_bf16.h>
#include <math.h>

// out[b,f,t] = sum_l sig[b,l] * win[t,l] * cos(2*pi*fv[f]*l/8192)
// R16 = R14 (best: single dispatch, zero ws, 2-b amortization, register-
// direct fragments) with MFMA shape 16x16x32 -> 32x32x16:
//  - 2x FLOP per MFMA instruction at the same per-lane operand count
//    (8 A-els + 8 B-els) -> half the MFMA instructions per wave;
//  - one (tc, fv) per lane (t = f = lane&31) -> prologue trans halves;
//  - K-step 16 ping-pong Chebyshev/Gaussian recurrences (64 steps/wave).
// Block: 32t x 32f x 2b, 8 waves split K=8192; grid 256. Everything else
// (staging, LDS union, two-phase reduce) identical to R14.
// fv/tc = linspace->int32 reproduced exactly in fp32 (R0-verified).
// 32x32 C/D layout: col=lane&31, row=(reg&3)+8*(reg>>2)+4*(lane>>5).

#define L_ 8192
#define B_ 32

typedef _Float16 half8 __attribute__((ext_vector_type(8)));
typedef __fp16 fp16x2 __attribute__((ext_vector_type(2)));
typedef float float2v __attribute__((ext_vector_type(2)));
typedef float float4v __attribute__((ext_vector_type(4)));
typedef float float16v __attribute__((ext_vector_type(16)));

#define H_ 0.001220703125f                 // 1/819.2 = 5/4096 (exact)
#define CSTEP_ 7.66990393942594528198e-4f  // 2*pi/8192
#define DLT_ 0.01953125f                   // 16*H (exact)
#define DLT2H_ 1.9073486328125e-4f         // (16*H)^2 / 2 (exact)
#define Q16_ 0.99961860303f                // exp(-(16*H)^2)

__global__ __launch_bounds__(512, 2) void gabor_kernel(
    const float* __restrict__ signal, float* __restrict__ out) {
  const int bx = blockIdx.x;  // 256 = bp16 * th4 * fh4
  const int bp = bx & 15;     // b-pair: b = 2*bp, 2*bp+1
  const int th = (bx >> 4) & 3;
  const int fh = (bx >> 6) & 3;
  const int tid = threadIdx.x;  // 512
  const int lane = tid & 63;
  const int wv = tid >> 6;      // 0..7
  const int row32 = lane & 31;  // A row (t) and B col (f) for this lane
  const int kg = lane >> 5;     // k subgroup (0/1) within K=16

  // LDS union: Sg lives during the K-loop, Acc (reduction) after it.
  __shared__ __align__(16) char smraw[32768];
  _Float16(*Sg)[L_] = (_Float16(*)[L_])smraw;       // [2][8192] f16, 32 KB
  float4v(*Acc)[64][4] = (float4v(*)[64][4])smraw;  // [8][64][4], 32 KB

  // ---- stage sig rows 2bp, 2bp+1 (once) ----
#pragma unroll
  for (int bi = 0; bi < 2; ++bi) {
    const float* srow = signal + (size_t)(2 * bp + bi) * L_;
#pragma unroll
    for (int i = 0; i < 2; ++i) {
      const int off = i * 4096 + tid * 8;
      float4v s0 = *(const float4v*)(srow + off);
      float4v s1 = *(const float4v*)(srow + off + 4);
      union { fp16x2 h2[4]; half8 h8; } sh;
      sh.h2[0] = __builtin_amdgcn_cvt_pkrtz(s0[0], s0[1]);
      sh.h2[1] = __builtin_amdgcn_cvt_pkrtz(s0[2], s0[3]);
      sh.h2[2] = __builtin_amdgcn_cvt_pkrtz(s1[0], s1[1]);
      sh.h2[3] = __builtin_amdgcn_cvt_pkrtz(s1[2], s1[3]);
      *(half8*)&Sg[bi][off] = sh.h8;
    }
  }
  __syncthreads();

  const int t0 = th * 32;
  const int f0 = fh * 32;
  const int k0 = wv * 1024 + kg * 8;  // element j=0 at step 0; +16 per step

  // ---- per-lane fragment state (packed f32 pairs), ONE t/f row per lane --
  float2v w2[4], Rw2[4];   // Gaussian value + step-ratio (8 els)
  float2v cE2[4], cO2[4];  // Chebyshev ping-pong (8 els)
  float2v K16v;
  const float2v Q16v = {Q16_, Q16_};
  {
    const float tc = truncf((float)(t0 + row32) * (8191.0f / 127.0f));
    const int fv = (int)((float)(f0 + row32) * (4096.0f / 127.0f));
    const float K16 = 2.0f * __cosf((float)((fv * 16) & (L_ - 1)) * CSTEP_);
    K16v = (float2v){K16, K16};
#pragma unroll
    for (int q = 0; q < 4; ++q) {
#pragma unroll
      for (int h = 0; h < 2; ++h) {
        const int j = 2 * q + h;
        const float x = ((float)(k0 + j) - tc) * H_;
        w2[q][h] = __expf(-0.5f * x * x);
        // ratio for k += 16: exp(-16*H*x - (16H)^2/2)
        Rw2[q][h] = __expf(__builtin_fmaf(-DLT_, x, -DLT2H_));
        cE2[q][h] = __cosf((float)((fv * (k0 + j)) & (L_ - 1)) * CSTEP_);
        // value at k-16 (k0+j+8176 == k0+j-16 mod 8192)
        cO2[q][h] =
            __cosf((float)((fv * (k0 + j + 8176)) & (L_ - 1)) * CSTEP_);
      }
    }
  }

  float16v acc[2];  // per b; 32 VGPRs total
  acc[0] = (float16v)(0.0f);
  acc[1] = (float16v)(0.0f);

  union H8 { fp16x2 h2[4]; half8 h8; };

  // ---- 64 K-steps (K=16 each): 32 rolled iterations x 2 ping-pong ----
#pragma unroll 1
  for (int p = 0; p < 32; ++p) {
    const int kbase = k0 + p * 32;  // even sub-step k; odd = +16
    // even sub-step: fragments from w2, cE2
    {
      H8 ha, hc;
#pragma unroll
      for (int q = 0; q < 4; ++q) {
        ha.h2[q] = __builtin_amdgcn_cvt_pkrtz(w2[q][0], w2[q][1]);
        hc.h2[q] = __builtin_amdgcn_cvt_pkrtz(cE2[q][0], cE2[q][1]);
      }
      // advance recurrences early (overlap with MFMA)
#pragma unroll
      for (int q = 0; q < 4; ++q) {
        w2[q] *= Rw2[q];
        Rw2[q] *= Q16v;
        cO2[q] = __builtin_elementwise_fma(K16v, cE2[q], -cO2[q]);
      }
      const half8 sg0 = *(const half8*)&Sg[0][kbase];
      const half8 sg1 = *(const half8*)&Sg[1][kbase];
      acc[0] = __builtin_amdgcn_mfma_f32_32x32x16_f16(ha.h8, hc.h8 * sg0,
                                                      acc[0], 0, 0, 0);
      acc[1] = __builtin_amdgcn_mfma_f32_32x32x16_f16(ha.h8, hc.h8 * sg1,
                                                      acc[1], 0, 0, 0);
    }
    // odd sub-step: fragments from w2 (advanced), cO2
    {
      H8 ha, hc;
#pragma unroll
      for (int q = 0; q < 4; ++q) {
        ha.h2[q] = __builtin_amdgcn_cvt_pkrtz(w2[q][0], w2[q][1]);
        hc.h2[q] = __builtin_amdgcn_cvt_pkrtz(cO2[q][0], cO2[q][1]);
      }
#pragma unroll
      for (int q = 0; q < 4; ++q) {
        w2[q] *= Rw2[q];
        Rw2[q] *= Q16v;
        cE2[q] = __builtin_elementwise_fma(K16v, cO2[q], -cE2[q]);
      }
      const half8 sg0 = *(const half8*)&Sg[0][kbase + 16];
      const half8 sg1 = *(const half8*)&Sg[1][kbase + 16];
      acc[0] = __builtin_amdgcn_mfma_f32_32x32x16_f16(ha.h8, hc.h8 * sg0,
                                                      acc[0], 0, 0, 0);
      acc[1] = __builtin_amdgcn_mfma_f32_32x32x16_f16(ha.h8, hc.h8 * sg1,
                                                      acc[1], 0, 0, 0);
    }
  }

  // ---- two-phase reduction through LDS (reusing Sg space) ----
  // 32x32 D frag: col(f)=lane&31, row(t)=(reg&3)+8*(reg>>2)+4*(lane>>5)
#pragma unroll
  for (int bi = 0; bi < 2; ++bi) {
    __syncthreads();  // previous LDS use complete
#pragma unroll
    for (int g = 0; g < 4; ++g) {
      float4v v = {acc[bi][4 * g], acc[bi][4 * g + 1], acc[bi][4 * g + 2],
                   acc[bi][4 * g + 3]};
      Acc[wv][lane][g] = v;
    }
    __syncthreads();
    if (wv < 4) {
      float4v sum = Acc[0][lane][wv];
#pragma unroll
      for (int w = 1; w < 8; ++w) sum += Acc[w][lane][wv];
      const int f = f0 + (lane & 31);
      const int t = t0 + 8 * wv + 4 * (lane >> 5);  // + r (contiguous)
      *(float4v*)(out + ((size_t)((2 * bp + bi) * 128 + f)) * 128 + t) = sum;
    }
  }
}

extern "C" void kernel_launch(void* const* d_in, const int* in_sizes, int n_in,
                              void* d_out, int out_size, void* d_ws, size_t ws_size,
                              hipStream_t stream) {
  const float* signal = (const float*)d_in[0];
  float* out = (float*)d_out;
  gabor_kernel<<<dim3(256), dim3(512), 0, stream>>>(signal, out);
}

// Round 17
// 67.567 us; speedup vs baseline: 1.1779x; 1.0034x over previous
//
#include <hip/hip_runtime.h>
#include <hip/hip_bf16.h>
#include <math.h>

// out[b,f,t] = sum_l sig[b,l] * win[t,l] * cos(2*pi*fv[f]*l/8192)
// R17 = R16 (32x32x16 MFMA, 2-b amortization, register-direct fragments)
// + SOFTWARE-PIPELINED sig reads: iteration p issues the ds_reads for p+1
// into a shadow register set and computes with the current set, moving the
// LDS load->use distance from ~0 to a full iteration (~250+ cyc). Theory:
// R12-R16 all exposed raw ds_read latency per sub-step inside the rolled
// loop (the one invariant across six null experiments).
// fv/tc = linspace->int32 reproduced exactly in fp32 (R0-verified).
// 32x32 C/D layout: col=lane&31, row=(reg&3)+8*(reg>>2)+4*(lane>>5).

#define L_ 8192
#define B_ 32

typedef _Float16 half8 __attribute__((ext_vector_type(8)));
typedef __fp16 fp16x2 __attribute__((ext_vector_type(2)));
typedef float float2v __attribute__((ext_vector_type(2)));
typedef float float4v __attribute__((ext_vector_type(4)));
typedef float float16v __attribute__((ext_vector_type(16)));

#define H_ 0.001220703125f                 // 1/819.2 = 5/4096 (exact)
#define CSTEP_ 7.66990393942594528198e-4f  // 2*pi/8192
#define DLT_ 0.01953125f                   // 16*H (exact)
#define DLT2H_ 1.9073486328125e-4f         // (16*H)^2 / 2 (exact)
#define Q16_ 0.99961860303f                // exp(-(16*H)^2)

__global__ __launch_bounds__(512, 2) void gabor_kernel(
    const float* __restrict__ signal, float* __restrict__ out) {
  const int bx = blockIdx.x;  // 256 = bp16 * th4 * fh4
  const int bp = bx & 15;     // b-pair: b = 2*bp, 2*bp+1
  const int th = (bx >> 4) & 3;
  const int fh = (bx >> 6) & 3;
  const int tid = threadIdx.x;  // 512
  const int lane = tid & 63;
  const int wv = tid >> 6;      // 0..7
  const int row32 = lane & 31;  // A row (t) and B col (f) for this lane
  const int kg = lane >> 5;     // k subgroup (0/1) within K=16

  // LDS union: Sg lives during the K-loop, Acc (reduction) after it.
  __shared__ __align__(16) char smraw[32768];
  _Float16(*Sg)[L_] = (_Float16(*)[L_])smraw;       // [2][8192] f16, 32 KB
  float4v(*Acc)[64][4] = (float4v(*)[64][4])smraw;  // [8][64][4], 32 KB

  // ---- stage sig rows 2bp, 2bp+1 (once) ----
#pragma unroll
  for (int bi = 0; bi < 2; ++bi) {
    const float* srow = signal + (size_t)(2 * bp + bi) * L_;
#pragma unroll
    for (int i = 0; i < 2; ++i) {
      const int off = i * 4096 + tid * 8;
      float4v s0 = *(const float4v*)(srow + off);
      float4v s1 = *(const float4v*)(srow + off + 4);
      union { fp16x2 h2[4]; half8 h8; } sh;
      sh.h2[0] = __builtin_amdgcn_cvt_pkrtz(s0[0], s0[1]);
      sh.h2[1] = __builtin_amdgcn_cvt_pkrtz(s0[2], s0[3]);
      sh.h2[2] = __builtin_amdgcn_cvt_pkrtz(s1[0], s1[1]);
      sh.h2[3] = __builtin_amdgcn_cvt_pkrtz(s1[2], s1[3]);
      *(half8*)&Sg[bi][off] = sh.h8;
    }
  }
  __syncthreads();

  const int t0 = th * 32;
  const int f0 = fh * 32;
  const int k0 = wv * 1024 + kg * 8;  // element j=0 at step 0; +16 per step

  // ---- per-lane fragment state (packed f32 pairs), ONE t/f row per lane --
  float2v w2[4], Rw2[4];   // Gaussian value + step-ratio (8 els)
  float2v cE2[4], cO2[4];  // Chebyshev ping-pong (8 els)
  float2v K16v;
  const float2v Q16v = {Q16_, Q16_};
  {
    const float tc = truncf((float)(t0 + row32) * (8191.0f / 127.0f));
    const int fv = (int)((float)(f0 + row32) * (4096.0f / 127.0f));
    const float K16 = 2.0f * __cosf((float)((fv * 16) & (L_ - 1)) * CSTEP_);
    K16v = (float2v){K16, K16};
#pragma unroll
    for (int q = 0; q < 4; ++q) {
#pragma unroll
      for (int h = 0; h < 2; ++h) {
        const int j = 2 * q + h;
        const float x = ((float)(k0 + j) - tc) * H_;
        w2[q][h] = __expf(-0.5f * x * x);
        // ratio for k += 16: exp(-16*H*x - (16H)^2/2)
        Rw2[q][h] = __expf(__builtin_fmaf(-DLT_, x, -DLT2H_));
        cE2[q][h] = __cosf((float)((fv * (k0 + j)) & (L_ - 1)) * CSTEP_);
        // value at k-16 (k0+j+8176 == k0+j-16 mod 8192)
        cO2[q][h] =
            __cosf((float)((fv * (k0 + j + 8176)) & (L_ - 1)) * CSTEP_);
      }
    }
  }

  float16v acc[2];  // per b; 32 VGPRs total
  acc[0] = (float16v)(0.0f);
  acc[1] = (float16v)(0.0f);

  union H8 { fp16x2 h2[4]; half8 h8; };

  // ---- 64 K-steps (K=16): 32 rolled iterations x 2 ping-pong, with sig
  //      register prefetch one full iteration ahead ----
  half8 curE0 = *(const half8*)&Sg[0][k0];
  half8 curE1 = *(const half8*)&Sg[1][k0];
  half8 curO0 = *(const half8*)&Sg[0][k0 + 16];
  half8 curO1 = *(const half8*)&Sg[1][k0 + 16];

#pragma unroll 1
  for (int p = 0; p < 32; ++p) {
    // prefetch iteration p+1 (masked wrap avoids LDS OOB on last iter)
    const int kn = k0 + ((p + 1) & 31) * 32;
    half8 nxtE0 = *(const half8*)&Sg[0][kn];
    half8 nxtE1 = *(const half8*)&Sg[1][kn];
    half8 nxtO0 = *(const half8*)&Sg[0][kn + 16];
    half8 nxtO1 = *(const half8*)&Sg[1][kn + 16];

    // even sub-step: fragments from w2, cE2
    {
      H8 ha, hc;
#pragma unroll
      for (int q = 0; q < 4; ++q) {
        ha.h2[q] = __builtin_amdgcn_cvt_pkrtz(w2[q][0], w2[q][1]);
        hc.h2[q] = __builtin_amdgcn_cvt_pkrtz(cE2[q][0], cE2[q][1]);
      }
#pragma unroll
      for (int q = 0; q < 4; ++q) {
        w2[q] *= Rw2[q];
        Rw2[q] *= Q16v;
        cO2[q] = __builtin_elementwise_fma(K16v, cE2[q], -cO2[q]);
      }
      acc[0] = __builtin_amdgcn_mfma_f32_32x32x16_f16(ha.h8, hc.h8 * curE0,
                                                      acc[0], 0, 0, 0);
      acc[1] = __builtin_amdgcn_mfma_f32_32x32x16_f16(ha.h8, hc.h8 * curE1,
                                                      acc[1], 0, 0, 0);
    }
    // odd sub-step: fragments from w2 (advanced), cO2
    {
      H8 ha, hc;
#pragma unroll
      for (int q = 0; q < 4; ++q) {
        ha.h2[q] = __builtin_amdgcn_cvt_pkrtz(w2[q][0], w2[q][1]);
        hc.h2[q] = __builtin_amdgcn_cvt_pkrtz(cO2[q][0], cO2[q][1]);
      }
#pragma unroll
      for (int q = 0; q < 4; ++q) {
        w2[q] *= Rw2[q];
        Rw2[q] *= Q16v;
        cE2[q] = __builtin_elementwise_fma(K16v, cO2[q], -cE2[q]);
      }
      acc[0] = __builtin_amdgcn_mfma_f32_32x32x16_f16(ha.h8, hc.h8 * curO0,
                                                      acc[0], 0, 0, 0);
      acc[1] = __builtin_amdgcn_mfma_f32_32x32x16_f16(ha.h8, hc.h8 * curO1,
                                                      acc[1], 0, 0, 0);
    }
    curE0 = nxtE0;
    curE1 = nxtE1;
    curO0 = nxtO0;
    curO1 = nxtO1;
  }

  // ---- two-phase reduction through LDS (reusing Sg space) ----
  // 32x32 D frag: col(f)=lane&31, row(t)=(reg&3)+8*(reg>>2)+4*(lane>>5)
#pragma unroll
  for (int bi = 0; bi < 2; ++bi) {
    __syncthreads();  // previous LDS use complete
#pragma unroll
    for (int g = 0; g < 4; ++g) {
      float4v v = {acc[bi][4 * g], acc[bi][4 * g + 1], acc[bi][4 * g + 2],
                   acc[bi][4 * g + 3]};
      Acc[wv][lane][g] = v;
    }
    __syncthreads();
    if (wv < 4) {
      float4v sum = Acc[0][lane][wv];
#pragma unroll
      for (int w = 1; w < 8; ++w) sum += Acc[w][lane][wv];
      const int f = f0 + (lane & 31);
      const int t = t0 + 8 * wv + 4 * (lane >> 5);  // + r (contiguous)
      *(float4v*)(out + ((size_t)((2 * bp + bi) * 128 + f)) * 128 + t) = sum;
    }
  }
}

extern "C" void kernel_launch(void* const* d_in, const int* in_sizes, int n_in,
                              void* d_out, int out_size, void* d_ws, size_t ws_size,
                              hipStream_t stream) {
  const float* signal = (const float*)d_in[0];
  float* out = (float*)d_out;
  gabor_kernel<<<dim3(256), dim3(512), 0, stream>>>(signal, out);
}